// Round 1
// baseline (207.160 us; speedup 1.0000x reference)
//
#include <hip/hip_runtime.h>
#include <stdint.h>

// ListwiseLoss: B=524288 rows, H=32. One THREAD per row, coalesced global
// reads via per-wave LDS staging. Round-8 restructuring: 16-bit staging.
//   kl_row = sum_valid e_i*(s_i - g_i) / se,  e = exp(s),
//   g_i = s of the (rank_i)-th valid element in index order
// (max-sub and log(se) cancel between the KL sums; eps dropped — validated
//  rounds 1-7, absmax 0.0).
//
// Round-8 changes (occupancy/latency attack; counters showed 34% occupancy,
// 41% VALU, 15% HBM — latency-bound with LDS as the occupancy limiter):
//  * Mask is folded into the RANK staging phase: staged value per element is
//    t = valid ? (r<<5) : 0x4000  (u16). Reader ORs in the element index
//    (known from position) to form the sort key. Mask staging round trip
//    and vbits SWAR are GONE (3 LDS phases -> 2).
//  * Scores converted f32->bf16 BEFORE staging (consumed as bf16 anyway).
//  * Staged row: 16 dwords of u16-pairs + 1 pad dword = 17 dwords (odd
//    stride -> bank-rotated, conflict-free reads). Per-wave region 4352 B,
//    per-block LDS 17.4 KB (was 34.3 KB) -> 8 blocks/CU by LDS instead of 4.
// Keys: key16=(r<<5)|idx, invalid -> 0x4000|idx (sorts last, bit14 set).
// 32x32 rank count = packed-i16 SWAR (round 7). Gather row overlays score
// row: write u16 slot jp <= 2a+1 < next read slot 2a+2; park slot = u16 33
// (dword 16, never read as score). Same-wave DS ordering; no __syncthreads
// in hot path.

#define H 32
#define BLK 256
#define WPB 4
#define ROWD 17               // dwords per staged row (16 data + 1 pad)
#define WREGION (64 * ROWD)   // 1088 dwords = 4352 B per wave

typedef short s16x2 __attribute__((ext_vector_type(2)));
union PK { uint32_t u; s16x2 v; };

__global__ __launch_bounds__(BLK) void listwise_kernel(
    const float* __restrict__ scores,
    const int* __restrict__ rankings,
    const unsigned char* __restrict__ mask_u8,
    float* __restrict__ part_kl,
    float* __restrict__ part_cnt,
    int nrows)
{
    __shared__ uint32_t stage[WPB * WREGION];   // 17408 B
    __shared__ float s_kl[WPB], s_cnt[WPB];

    const int tid  = threadIdx.x;
    const int lane = tid & 63;
    const int wid  = tid >> 6;
    uint32_t* wbuf = &stage[wid * WREGION];
    const int wrow0 = blockIdx.x * BLK + wid * 64;   // wave's 64 rows

    // mask dtype detect (bool=1B vs int32=4B); wave-uniform branch
    unsigned char probe = mask_u8[lane];
    const bool mask_is_i32 =
        (__ballot(((lane & 3) != 0) && (probe != 0)) == 0ull);

    float kl = 0.0f, cnt = 0.0f;

    uint32_t kp[16], sp[16];
    int nv = 0;
    bool have_row = false;
    unsigned short* rowp = (unsigned short*)&wbuf[lane * ROWD];

    if (wrow0 + 64 <= nrows) {
        have_row = true;

        // ======= phase A: mask+rankings -> staged u16 key (sans idx) =======
        const uint4* r4 = (const uint4*)(rankings + (size_t)wrow0 * H);
        if (mask_is_i32) {
            const uint4* m4 =
                (const uint4*)((const uint32_t*)mask_u8 + (size_t)wrow0 * H);
            #pragma unroll
            for (int c = 0; c < 8; ++c) {
                const uint4 rv = r4[lane + 64 * c];
                const uint4 mv = m4[lane + 64 * c];
                const int L = (lane + 64 * c) << 2;   // element idx 0..2047
                const uint32_t t0 = (mv.x != 0u && (int)rv.x > 0) ? (rv.x << 5) : 0x4000u;
                const uint32_t t1 = (mv.y != 0u && (int)rv.y > 0) ? (rv.y << 5) : 0x4000u;
                const uint32_t t2 = (mv.z != 0u && (int)rv.z > 0) ? (rv.z << 5) : 0x4000u;
                const uint32_t t3 = (mv.w != 0u && (int)rv.w > 0) ? (rv.w << 5) : 0x4000u;
                uint32_t* d = &wbuf[(L >> 5) * ROWD + ((L & 31) >> 1)];
                d[0] = t0 | (t1 << 16);
                d[1] = t2 | (t3 << 16);
            }
        } else {
            const uint32_t* m1 = (const uint32_t*)(mask_u8 + (size_t)wrow0 * H);
            #pragma unroll
            for (int c = 0; c < 8; ++c) {
                const uint4 rv = r4[lane + 64 * c];
                const uint32_t mv = m1[lane + 64 * c];  // 4 mask bytes, same elems
                const int L = (lane + 64 * c) << 2;
                const uint32_t t0 = ((mv & 0x000000FFu) != 0u && (int)rv.x > 0) ? (rv.x << 5) : 0x4000u;
                const uint32_t t1 = ((mv & 0x0000FF00u) != 0u && (int)rv.y > 0) ? (rv.y << 5) : 0x4000u;
                const uint32_t t2 = ((mv & 0x00FF0000u) != 0u && (int)rv.z > 0) ? (rv.z << 5) : 0x4000u;
                const uint32_t t3 = ((mv & 0xFF000000u) != 0u && (int)rv.w > 0) ? (rv.w << 5) : 0x4000u;
                uint32_t* d = &wbuf[(L >> 5) * ROWD + ((L & 31) >> 1)];
                d[0] = t0 | (t1 << 16);
                d[1] = t2 | (t3 << 16);
            }
        }
        // read back own row: build packed keys + count valid via bit14 SWAR
        {
            const uint32_t* rb = &wbuf[lane * ROWD];
            uint32_t inv2 = 0;
            #pragma unroll
            for (int a = 0; a < 16; ++a) {
                const uint32_t w = rb[a];
                kp[a] = w | ((uint32_t)(2 * a) | (((uint32_t)(2 * a + 1)) << 16));
                inv2 += (w >> 14) & 0x00010001u;   // invalid flag per half
            }
            nv = 32 - (int)((inv2 & 0xFFFFu) + (inv2 >> 16));
        }

        // ===== phase B: scores -> staged bf16 pairs + gather compaction =====
        {
            const uint4* g4 = (const uint4*)(scores + (size_t)wrow0 * H);
            #pragma unroll
            for (int c = 0; c < 8; ++c) {
                const uint4 v = g4[lane + 64 * c];
                const int L = (lane + 64 * c) << 2;
                const uint32_t b0 = (v.x + 0x8000u) >> 16;   // bf16 rnd
                const uint32_t b1 = (v.y + 0x8000u) >> 16;
                const uint32_t b2 = (v.z + 0x8000u) >> 16;
                const uint32_t b3 = (v.w + 0x8000u) >> 16;
                uint32_t* d = &wbuf[(L >> 5) * ROWD + ((L & 31) >> 1)];
                d[0] = b0 | (b1 << 16);
                d[1] = b2 | (b3 << 16);
            }
            const uint32_t* rb = &wbuf[lane * ROWD];
            int jp = 0;
            #pragma unroll
            for (int a = 0; a < 16; ++a) {
                const uint32_t sw = rb[a];
                sp[a] = sw;
                const uint32_t kw = kp[a];
                const bool v0 = (kw & 0xFFFFu) < 0x4000u;
                const bool v1 = (kw >> 16) < 0x4000u;
                rowp[v0 ? jp : 33] = (unsigned short)(sw & 0xFFFFu); // park->33
                jp += v0 ? 1 : 0;
                rowp[v1 ? jp : 33] = (unsigned short)(sw >> 16);
                jp += v1 ? 1 : 0;
            }
        }
    } else if (wrow0 + lane < nrows) {
        // ---- tail (never hit at B=524288): per-thread scalar path
        have_row = true;
        const int row = wrow0 + lane;
        const int*   rptr = rankings + (size_t)row * H;
        const float* sptr = scores + (size_t)row * H;
        uint32_t vbits = 0;
        if (mask_is_i32) {
            const int* mp = (const int*)mask_u8 + (size_t)row * H;
            #pragma unroll
            for (int k = 0; k < H; ++k) vbits |= (mp[k] != 0 ? 1u : 0u) << k;
        } else {
            const unsigned char* mp = mask_u8 + (size_t)row * H;
            #pragma unroll
            for (int k = 0; k < H; ++k) vbits |= (mp[k] != 0 ? 1u : 0u) << k;
        }
        int jp = 0;
        #pragma unroll
        for (int a = 0; a < 16; ++a) {
            uint32_t kq[2], bq[2];
            #pragma unroll
            for (int q = 0; q < 2; ++q) {
                const int k = 2 * a + q;
                const int r = rptr[k];
                const bool valid = (((vbits >> k) & 1u) != 0u) && (r > 0);
                kq[q] = valid ? ((((uint32_t)r) << 5) | (uint32_t)k)
                              : (0x4000u | (uint32_t)k);
                nv += valid ? 1 : 0;
                bq[q] = (__float_as_uint(sptr[k]) + 0x8000u) >> 16;
                rowp[valid ? jp : 33] = (unsigned short)bq[q];
                jp += valid ? 1 : 0;
            }
            kp[a] = kq[0] | (kq[1] << 16);
            sp[a] = bq[0] | (bq[1] << 16);
        }
    }

    if (have_row) {
        // ===== phase C: SWAR rank-count, gather, accumulate =====
        float se = 0.0f, num = 0.0f;
        #pragma unroll
        for (int i = 0; i < H; ++i) {
            const uint32_t pw = kp[i / 2];
            const uint32_t k16 = (i & 1) ? (pw >> 16) : (pw & 0xFFFFu);
            PK b; b.u = (k16 << 16) | k16;
            PK acc; acc.u = 0;
            #pragma unroll
            for (int m = 0; m < 16; ++m) {
                PK pm; pm.u = kp[m];
                s16x2 d = pm.v - b.v;            // v_pk_sub_i16
                acc.v = acc.v - (d >> 15);       // +1 per (key_m < key_i)
            }
            const int j = (int)acc.v.x + (int)acc.v.y;   // rank 0..31
            const float g = __uint_as_float(((uint32_t)rowp[j]) << 16);
            const uint32_t sw = sp[i / 2];
            const float s_i = __uint_as_float((i & 1) ? (sw & 0xFFFF0000u)
                                                      : (sw << 16));
            const bool valid = k16 < 0x4000u;
            float e = __expf(s_i);
            e = valid ? e : 0.0f;
            const float d2 = valid ? (s_i - g) : 0.0f;
            se += e;
            num = __builtin_fmaf(e, d2, num);
        }
        if (nv > 1) { kl = __fdividef(num, se); cnt = 1.0f; }
    }

    // ---- block reduction; unconditional partial write (no memset/atomics)
    #pragma unroll
    for (int m = 32; m >= 1; m >>= 1) {
        kl  += __shfl_xor(kl, m);
        cnt += __shfl_xor(cnt, m);
    }
    if (lane == 0) { s_kl[wid] = kl; s_cnt[wid] = cnt; }
    __syncthreads();
    if (tid == 0) {
        part_kl[blockIdx.x]  = s_kl[0] + s_kl[1] + s_kl[2] + s_kl[3];
        part_cnt[blockIdx.x] = s_cnt[0] + s_cnt[1] + s_cnt[2] + s_cnt[3];
    }
}

__global__ __launch_bounds__(256) void finalize_kernel(
    const float* __restrict__ part_kl,
    const float* __restrict__ part_cnt,
    float* __restrict__ out, int nblk)
{
    float k = 0.0f, c = 0.0f;
    for (int i = threadIdx.x; i < nblk; i += 256) {
        k += part_kl[i];
        c += part_cnt[i];
    }
    #pragma unroll
    for (int m = 32; m >= 1; m >>= 1) {
        k += __shfl_xor(k, m);
        c += __shfl_xor(c, m);
    }
    __shared__ float sk[4], sc[4];
    const int wid = threadIdx.x >> 6;
    if ((threadIdx.x & 63) == 0) { sk[wid] = k; sc[wid] = c; }
    __syncthreads();
    if (threadIdx.x == 0) {
        float K = sk[0] + sk[1] + sk[2] + sk[3];
        float C = sc[0] + sc[1] + sc[2] + sc[3];
        if (C < 1.0f) C = 1.0f;
        out[0] = K / C;
    }
}

extern "C" void kernel_launch(void* const* d_in, const int* in_sizes, int n_in,
                              void* d_out, int out_size, void* d_ws, size_t ws_size,
                              hipStream_t stream) {
    const float* scores = (const float*)d_in[0];
    const int* rankings = (const int*)d_in[1];
    const unsigned char* mask = (const unsigned char*)d_in[2];
    float* out = (float*)d_out;

    const int total = in_sizes[0];       // B*H = 16777216
    const int nrows = total / H;         // 524288 rows
    const int blocks = (nrows + BLK - 1) / BLK;   // 2048

    float* part_kl  = (float*)d_ws;               // [0, blocks)
    float* part_cnt = (float*)d_ws + blocks;      // [blocks, 2*blocks)

    listwise_kernel<<<blocks, BLK, 0, stream>>>(
        scores, rankings, mask, part_kl, part_cnt, nrows);

    finalize_kernel<<<1, 256, 0, stream>>>(part_kl, part_cnt, out, blocks);
}